// Round 9
// baseline (147.626 us; speedup 1.0000x reference)
//
#include <hip/hip_runtime.h>
#include <hip/hip_bf16.h>
#include <stdint.h>

typedef __hip_bfloat16 bf16_t;
typedef __attribute__((ext_vector_type(8))) __bf16 bf16x8;
typedef __attribute__((ext_vector_type(4))) float floatx4;
typedef __attribute__((ext_vector_type(16))) float floatx16;

#define BM 128
#define BN 128
#define BK 64

// async 16B global->LDS (wave-uniform LDS base + lane*16; our layouts satisfy this)
__device__ inline void async_load16(const void* g, void* l) {
  __builtin_amdgcn_global_load_lds(
      (const __attribute__((address_space(1))) unsigned int*)g,
      (__attribute__((address_space(3))) unsigned int*)l,
      16, 0, 0);
}

__device__ inline unsigned short bf16_bits(float f) {
  bf16_t b = __float2bfloat16(f);
  return *(const unsigned short*)&b;
}

// fp32 -> bf16 for all 5 tensors + S zero-init, one launch.
__global__ void cvt_all(const float* __restrict__ h, const float* __restrict__ Wq,
                        const float* __restrict__ Wk, const float* __restrict__ Wv,
                        const float* __restrict__ Wo,
                        bf16_t* __restrict__ hb, bf16_t* __restrict__ Wqb,
                        bf16_t* __restrict__ Wkb, bf16_t* __restrict__ Wvb,
                        bf16_t* __restrict__ Wob, float* __restrict__ S)
{
  const int bid = blockIdx.x;
  if (bid >= 8192) {
    float4* s4 = (float4*)S;      // 131072 floats = 32768 float4
    const int base = (bid - 8192) * 256 + threadIdx.x;   // 0..511
#pragma unroll
    for (int i = 0; i < 64; ++i)
      s4[base + i * 512] = (float4){0.f, 0.f, 0.f, 0.f};
    return;
  }
  const float* s; bf16_t* d; int base;
  if (bid < 4096)      { s = h;  d = hb;  base = bid; }
  else if (bid < 5120) { s = Wq; d = Wqb; base = bid - 4096; }
  else if (bid < 6144) { s = Wk; d = Wkb; base = bid - 5120; }
  else if (bid < 7168) { s = Wv; d = Wvb; base = bid - 6144; }
  else                 { s = Wo; d = Wob; base = bid - 7168; }
  const int i = (base * 256 + threadIdx.x) * 4;
  float4 f = *(const float4*)(s + i);
  union { unsigned short u[4]; uint2 v; } p;
  p.u[0] = bf16_bits(f.x); p.u[1] = bf16_bits(f.y);
  p.u[2] = bf16_bits(f.z); p.u[3] = bf16_bits(f.w);
  *(uint2*)(d + i) = p.v;
}

// QKV GEMM: C[M,N] = A[M,K] * B[N,K]^T ; bf16; fp32 accum; 32x32x16 MFMA.
// mat0 -> Qbuf row-major; mat1/mat2 -> Kt/Vt TRANSPOSED [bh][64][2048 m].
// A/B frag: m=lane&31, k=(lane>>5)*8+j.  C/D: col=lane&31, row=(reg&3)+8*(reg>>2)+4*(lane>>5).
// XOR swizzle: LDS granule slot g of row r holds global granule g^(r&7).
__global__ __launch_bounds__(256, 2)
void gemm_qkv(const bf16_t* __restrict__ A, int lda,
              const bf16_t* __restrict__ B0, const bf16_t* __restrict__ B1,
              const bf16_t* __restrict__ B2,
              bf16_t* __restrict__ Qbuf,
              bf16_t* __restrict__ Kt, bf16_t* __restrict__ Vt)
{
  __shared__ alignas(16) __bf16 As[BM * BK];
  __shared__ alignas(16) __bf16 Bs[BN * BK];

  const int t = threadIdx.x;
  const int lane = t & 63;
  const int wave = t >> 6;
  const int wm = wave >> 1;   // 0..1
  const int wn = wave & 1;    // 0..1
  const int lrow = lane & 31;       // fragment row
  const int lkg = lane >> 5;        // k half-chunk select

  const int m0 = blockIdx.x * BM;
  const int nblk = blockIdx.y * BN;
  const int mat = nblk >> 10;
  const bf16_t* __restrict__ B = (mat == 0) ? B0 : ((mat == 1) ? B1 : B2);
  const int n0 = nblk & 1023;

  floatx16 acc[2][2];
#pragma unroll
  for (int i = 0; i < 2; ++i)
#pragma unroll
    for (int j = 0; j < 2; ++j)
#pragma unroll
      for (int r = 0; r < 16; ++r) acc[i][j][r] = 0.f;

  const int srow = t >> 3;   // staging row within 32-row chunk
  const int sgs = t & 7;     // LDS granule slot

  for (int k0 = 0; k0 < 1024; k0 += BK) {
#pragma unroll
    for (int r4 = 0; r4 < 4; ++r4) {
      const int row = r4 * 32 + srow;
      const int gsrc = sgs ^ (row & 7);
      async_load16(A + (size_t)(m0 + row) * lda + k0 + gsrc * 8,
                   &As[row * BK + sgs * 8]);
      async_load16(B + (size_t)(n0 + row) * 1024 + k0 + gsrc * 8,
                   &Bs[row * BK + sgs * 8]);
    }
    __syncthreads();
#pragma unroll
    for (int c = 0; c < 4; ++c) {       // k chunks of 16
      bf16x8 af[2], bfv[2];
      const int g = c * 2 + lkg;
#pragma unroll
      for (int i = 0; i < 2; ++i) {
        const int row = wm * 64 + i * 32 + lrow;
        af[i] = *(const bf16x8*)&As[row * BK + (g ^ (row & 7)) * 8];
      }
#pragma unroll
      for (int j = 0; j < 2; ++j) {
        const int row = wn * 64 + j * 32 + lrow;
        bfv[j] = *(const bf16x8*)&Bs[row * BK + (g ^ (row & 7)) * 8];
      }
#pragma unroll
      for (int i = 0; i < 2; ++i)
#pragma unroll
        for (int j = 0; j < 2; ++j)
          acc[i][j] = __builtin_amdgcn_mfma_f32_32x32x16_bf16(
              af[i], bfv[j], acc[i][j], 0, 0, 0);
    }
    __syncthreads();
  }

  const int ccol = lane & 31;
  const int crow4 = 4 * (lane >> 5);

  if (mat != 0) {
    bf16_t* __restrict__ T = (mat == 1) ? Kt : Vt;
#pragma unroll
    for (int i = 0; i < 2; ++i) {
#pragma unroll
      for (int j = 0; j < 2; ++j) {
#pragma unroll
        for (int q = 0; q < 4; ++q) {
          const int lc = n0 + wn * 64 + j * 32 + ccol;        // 0..1023
          const int hidx = lc >> 6, d = lc & 63;
          const int grow = m0 + wm * 64 + i * 32 + 8 * q + crow4;
          const int bidx = grow >> 11, mloc = grow & 2047;
          union { unsigned short u[4]; uint2 v; } p;
#pragma unroll
          for (int r = 0; r < 4; ++r) p.u[r] = bf16_bits(acc[i][j][q * 4 + r]);
          *(uint2*)(T + (((size_t)bidx * 16 + hidx) * 64 + d) * 2048 + mloc) = p.v;
        }
      }
    }
    return;
  }

#pragma unroll
  for (int i = 0; i < 2; ++i) {
#pragma unroll
    for (int j = 0; j < 2; ++j) {
#pragma unroll
      for (int q = 0; q < 4; ++q) {
        const int gcol = n0 + wn * 64 + j * 32 + ccol;
        const int grow = m0 + wm * 64 + i * 32 + 8 * q + crow4;
#pragma unroll
        for (int r = 0; r < 4; ++r)
          Qbuf[(size_t)(grow + r) * 1024 + gcol] = __float2bfloat16(acc[i][j][q * 4 + r]);
      }
    }
  }
}

// S[bh][d][e] += sum_m Kt[bh][d][m] * Vt[bh][e][m]  -- NT MFMA GEMM (16x16x32).
// grid (32 bh, 8 ksplit); fp32 atomic epilogue (tiny, L2-resident).
__global__ __launch_bounds__(256, 2)
void ktv_gemm(const bf16_t* __restrict__ Kt, const bf16_t* __restrict__ Vt,
              float* __restrict__ S)
{
  __shared__ alignas(16) __bf16 As[64 * 64];   // Kt tile (d rows)
  __shared__ alignas(16) __bf16 Bs[64 * 64];   // Vt tile (e rows)

  const int t = threadIdx.x;
  const int lane = t & 63;
  const int wave = t >> 6;            // d-strip = wave*16
  const int bh = blockIdx.x;
  const int kc = blockIdx.y;          // k-range kc*256 .. +256

  const bf16_t* A = Kt + (size_t)bh * 64 * 2048;
  const bf16_t* B = Vt + (size_t)bh * 64 * 2048;

  floatx4 acc[4];
#pragma unroll
  for (int j = 0; j < 4; ++j) acc[j] = (floatx4){0.f, 0.f, 0.f, 0.f};

  const int srow = t >> 3;   // 0..31
  const int sgs = t & 7;

  for (int k0 = kc * 256; k0 < kc * 256 + 256; k0 += 64) {
#pragma unroll
    for (int r2 = 0; r2 < 2; ++r2) {
      const int row = r2 * 32 + srow;
      const int gsrc = sgs ^ (row & 7);
      async_load16(A + (size_t)row * 2048 + k0 + gsrc * 8, &As[row * 64 + sgs * 8]);
      async_load16(B + (size_t)row * 2048 + k0 + gsrc * 8, &Bs[row * 64 + sgs * 8]);
    }
    __syncthreads();
#pragma unroll
    for (int ks = 0; ks < 2; ++ks) {
      bf16x8 af, bfv[4];
      {
        const int row = wave * 16 + (lane & 15);
        const int g = ks * 4 + (lane >> 4);
        af = *(const bf16x8*)&As[row * 64 + (g ^ (row & 7)) * 8];
      }
#pragma unroll
      for (int j = 0; j < 4; ++j) {
        const int row = j * 16 + (lane & 15);
        const int g = ks * 4 + (lane >> 4);
        bfv[j] = *(const bf16x8*)&Bs[row * 64 + (g ^ (row & 7)) * 8];
      }
#pragma unroll
      for (int j = 0; j < 4; ++j)
        acc[j] = __builtin_amdgcn_mfma_f32_16x16x32_bf16(af, bfv[j], acc[j], 0, 0, 0);
    }
    __syncthreads();
  }

  // C[d][e]: d = wave*16 + crow + r, e = j*16 + ccol
  const int ccol = lane & 15;
  const int crow = (lane >> 4) * 4;
  float* Sp = S + (size_t)bh * 4096;
#pragma unroll
  for (int j = 0; j < 4; ++j)
#pragma unroll
    for (int r = 0; r < 4; ++r)
      unsafeAtomicAdd(&Sp[(wave * 16 + crow + r) * 64 + j * 16 + ccol], acc[j][r]);
}

// W_effT[b][n][h*64+d] = sum_e Wo[n][h*64+e] * S[bh][d][e]   (16x16x32 MFMA)
__global__ __launch_bounds__(256, 2)
void weff_mfma(const bf16_t* __restrict__ Wob, const float* __restrict__ S,
               bf16_t* __restrict__ WeffT)
{
  __shared__ alignas(16) __bf16 Aw[128 * 64];
  __shared__ alignas(16) __bf16 Sb[64 * 64];

  const int t = threadIdx.x;
  const int lane = t & 63;
  const int wave = t >> 6;          // 0..3 -> 32-row n strip
  const int bh = blockIdx.x;
  const int b = bh >> 4, hh = bh & 15;
  const int nt = blockIdx.y;        // 0..7 -> 128 n rows

  const bf16_t* wbase = Wob + (size_t)(nt * 128) * 1024 + hh * 64;
  const int srow = t >> 3;          // 0..31
  const int sgs = t & 7;
#pragma unroll
  for (int r4 = 0; r4 < 4; ++r4) {
    const int row = r4 * 32 + srow;
    const int gsrc = sgs ^ (row & 7);
    async_load16(wbase + (size_t)row * 1024 + gsrc * 8, &Aw[row * 64 + sgs * 8]);
  }
  // stage S (fp32 -> bf16), XOR-swizzled; rows = d, cols = e
  {
    const int r = t >> 2;           // 0..63 (d row)
    const int g0 = (t & 3) * 2;
    const float* sp = S + (size_t)bh * 4096 + r * 64;
#pragma unroll
    for (int gg = 0; gg < 2; ++gg) {
      const int g = g0 + gg;
      const int gs = g ^ (r & 7);
      const float4 f0 = *(const float4*)(sp + gs * 8);
      const float4 f1 = *(const float4*)(sp + gs * 8 + 4);
      union { unsigned short u[8]; uint4 v; } pk;
      pk.u[0] = bf16_bits(f0.x); pk.u[1] = bf16_bits(f0.y);
      pk.u[2] = bf16_bits(f0.z); pk.u[3] = bf16_bits(f0.w);
      pk.u[4] = bf16_bits(f1.x); pk.u[5] = bf16_bits(f1.y);
      pk.u[6] = bf16_bits(f1.z); pk.u[7] = bf16_bits(f1.w);
      *(uint4*)&Sb[r * 64 + g * 8] = pk.v;
    }
  }
  __syncthreads();

  floatx4 acc[2][4];
#pragma unroll
  for (int i = 0; i < 2; ++i)
#pragma unroll
    for (int j = 0; j < 4; ++j)
      acc[i][j] = (floatx4){0.f, 0.f, 0.f, 0.f};

#pragma unroll
  for (int ks = 0; ks < 2; ++ks) {
    bf16x8 af[2], bfv[4];
#pragma unroll
    for (int i = 0; i < 2; ++i) {
      const int row = wave * 32 + i * 16 + (lane & 15);
      const int g = ks * 4 + (lane >> 4);
      af[i] = *(const bf16x8*)&Aw[row * 64 + (g ^ (row & 7)) * 8];
    }
#pragma unroll
    for (int j = 0; j < 4; ++j) {
      const int row = j * 16 + (lane & 15);       // d
      const int g = ks * 4 + (lane >> 4);
      bfv[j] = *(const bf16x8*)&Sb[row * 64 + (g ^ (row & 7)) * 8];
    }
#pragma unroll
    for (int i = 0; i < 2; ++i)
#pragma unroll
      for (int j = 0; j < 4; ++j)
        acc[i][j] = __builtin_amdgcn_mfma_f32_16x16x32_bf16(
            af[i], bfv[j], acc[i][j], 0, 0, 0);
  }

  const int ccol = lane & 15;
  const int crow = (lane >> 4) * 4;
  bf16_t* Wt = WeffT + (size_t)b * 1024 * 1024;
#pragma unroll
  for (int i = 0; i < 2; ++i) {
#pragma unroll
    for (int j = 0; j < 4; ++j) {
      const int hd = hh * 64 + j * 16 + ccol;
      const int n = nt * 128 + wave * 32 + i * 16 + crow;
#pragma unroll
      for (int r = 0; r < 4; ++r)
        Wt[(size_t)(n + r) * 1024 + hd] = __float2bfloat16(acc[i][j][r]);
    }
  }
}

// out[m][n] = sum_hd Q[m][hd] * WeffT[b][n][hd]. 32x32x16 MFMA, direct fp32 stores.
// BM=64 x BN=128 tiles -> grid (64,8) = 512 blocks = 2 blocks/CU.
__global__ __launch_bounds__(256, 2)
void gemm_final(const bf16_t* __restrict__ Q, const bf16_t* __restrict__ WeffT,
                float* __restrict__ C)
{
  __shared__ alignas(16) __bf16 As[64 * BK];    // Q tile
  __shared__ alignas(16) __bf16 Bs[128 * BK];   // WeffT tile

  const int t = threadIdx.x;
  const int lane = t & 63;
  const int wave = t >> 6;
  const int wm = wave >> 1;   // 0..1 (32-row strips)
  const int wn = wave & 1;    // 0..1 (64-col strips)
  const int lrow = lane & 31;
  const int lkg = lane >> 5;

  const int m0 = blockIdx.x * 64;
  const int n0 = blockIdx.y * 128;
  const bf16_t* __restrict__ B = WeffT + (size_t)(m0 >> 11) * 1024 * 1024;

  floatx16 acc[2];
#pragma unroll
  for (int j = 0; j < 2; ++j)
#pragma unroll
    for (int r = 0; r < 16; ++r) acc[j][r] = 0.f;

  const int srow = t >> 3;
  const int sgs = t & 7;

  for (int k0 = 0; k0 < 1024; k0 += BK) {
#pragma unroll
    for (int r2 = 0; r2 < 2; ++r2) {
      const int row = r2 * 32 + srow;
      const int gsrc = sgs ^ (row & 7);
      async_load16(Q + (size_t)(m0 + row) * 1024 + k0 + gsrc * 8,
                   &As[row * BK + sgs * 8]);
    }
#pragma unroll
    for (int r4 = 0; r4 < 4; ++r4) {
      const int row = r4 * 32 + srow;
      const int gsrc = sgs ^ (row & 7);
      async_load16(B + (size_t)(n0 + row) * 1024 + k0 + gsrc * 8,
                   &Bs[row * BK + sgs * 8]);
    }
    __syncthreads();
#pragma unroll
    for (int c = 0; c < 4; ++c) {
      bf16x8 af, bfv[2];
      const int g = c * 2 + lkg;
      {
        const int row = wm * 32 + lrow;
        af = *(const bf16x8*)&As[row * BK + (g ^ (row & 7)) * 8];
      }
#pragma unroll
      for (int j = 0; j < 2; ++j) {
        const int row = wn * 64 + j * 32 + lrow;
        bfv[j] = *(const bf16x8*)&Bs[row * BK + (g ^ (row & 7)) * 8];
      }
#pragma unroll
      for (int j = 0; j < 2; ++j)
        acc[j] = __builtin_amdgcn_mfma_f32_32x32x16_bf16(af, bfv[j], acc[j], 0, 0, 0);
    }
    __syncthreads();
  }

  const int ccol = lane & 31;
  const int crow4 = 4 * (lane >> 5);
#pragma unroll
  for (int j = 0; j < 2; ++j) {
#pragma unroll
    for (int q = 0; q < 4; ++q) {
      const int gcol = n0 + wn * 64 + j * 32 + ccol;
      const int grow = m0 + wm * 32 + 8 * q + crow4;
#pragma unroll
      for (int r = 0; r < 4; ++r)
        C[(size_t)(grow + r) * 1024 + gcol] = acc[j][q * 4 + r];
    }
  }
}

extern "C" void kernel_launch(void* const* d_in, const int* in_sizes, int n_in,
                              void* d_out, int out_size, void* d_ws, size_t ws_size,
                              hipStream_t stream)
{
  const float* h  = (const float*)d_in[0];
  const float* Wq = (const float*)d_in[1];
  const float* Wk = (const float*)d_in[2];
  const float* Wv = (const float*)d_in[3];
  // d_in[4] = Wspan: dead code in reference
  const float* Wo = (const float*)d_in[5];
  float* out = (float*)d_out;

  char* ws = (char*)d_ws;
  bf16_t* hb    = (bf16_t*)(ws);                 // [4096,1024] bf16, 8 MB (dead after QKV)
  bf16_t* WeffT = (bf16_t*)(ws);                 // [2][1024,1024] bf16, 4 MB (reuses hb)
  bf16_t* Wqb   = (bf16_t*)(ws + (8u << 20));    // 2 MB each
  bf16_t* Wkb   = (bf16_t*)(ws + (10u << 20));
  bf16_t* Wvb   = (bf16_t*)(ws + (12u << 20));
  bf16_t* Wob   = (bf16_t*)(ws + (14u << 20));
  bf16_t* Qbuf  = (bf16_t*)(ws + (16u << 20));   // [4096,1024] bf16, 8 MB
  bf16_t* Kt    = (bf16_t*)(ws + (24u << 20));   // [32][64][2048] bf16, 8 MB
  bf16_t* Vt    = (bf16_t*)(ws + (32u << 20));   // [32][64][2048] bf16, 8 MB
  float*  S     = (float*) (ws + (40u << 20));   // [32][64][64] fp32, d-major

  // conversions + S zero (one launch)
  cvt_all<<<dim3(8194), 256, 0, stream>>>(h, Wq, Wk, Wv, Wo, hb, Wqb, Wkb, Wvb, Wob, S);

  // Q -> Qbuf; K,V -> Kt,Vt (transposed, m-contiguous)
  gemm_qkv<<<dim3(32, 24), 256, 0, stream>>>(hb, 1024, Wqb, Wkb, Wvb, Qbuf, Kt, Vt);
  // S[bh][d][e] = sum_m K*V (MFMA NT, split-K=8, atomic fp32 on tiny S)
  ktv_gemm<<<dim3(32, 8), 256, 0, stream>>>(Kt, Vt, S);
  // W_effT[b][n][hd] = sum_e Wo[n][he] * S[bh][d][e]  (overwrites dead hb)
  weff_mfma<<<dim3(32, 8), 256, 0, stream>>>(Wob, S, WeffT);
  // out = Q @ W_effT^T, direct fp32 stores, 2 blocks/CU
  gemm_final<<<dim3(64, 8), 256, 0, stream>>>(Qbuf, WeffT, out);
}

// Round 10
// 143.068 us; speedup vs baseline: 1.0319x; 1.0319x over previous
//
#include <hip/hip_runtime.h>
#include <hip/hip_bf16.h>
#include <stdint.h>

typedef __hip_bfloat16 bf16_t;
typedef __attribute__((ext_vector_type(8))) __bf16 bf16x8;
typedef __attribute__((ext_vector_type(4))) float floatx4;

#define BM 128
#define BN 128
#define BK 64

// async 16B global->LDS (wave-uniform LDS base + lane*16; our layouts satisfy this)
__device__ inline void async_load16(const void* g, void* l) {
  __builtin_amdgcn_global_load_lds(
      (const __attribute__((address_space(1))) unsigned int*)g,
      (__attribute__((address_space(3))) unsigned int*)l,
      16, 0, 0);
}

__device__ inline unsigned short bf16_bits(float f) {
  bf16_t b = __float2bfloat16(f);
  return *(const unsigned short*)&b;
}

// fp32 -> bf16 for all 5 tensors + S zero-init, one launch.
__global__ void cvt_all(const float* __restrict__ h, const float* __restrict__ Wq,
                        const float* __restrict__ Wk, const float* __restrict__ Wv,
                        const float* __restrict__ Wo,
                        bf16_t* __restrict__ hb, bf16_t* __restrict__ Wqb,
                        bf16_t* __restrict__ Wkb, bf16_t* __restrict__ Wvb,
                        bf16_t* __restrict__ Wob, float* __restrict__ S)
{
  const int bid = blockIdx.x;
  if (bid >= 8192) {
    float4* s4 = (float4*)S;      // 131072 floats = 32768 float4
    const int base = (bid - 8192) * 256 + threadIdx.x;   // 0..511
#pragma unroll
    for (int i = 0; i < 64; ++i)
      s4[base + i * 512] = (float4){0.f, 0.f, 0.f, 0.f};
    return;
  }
  const float* s; bf16_t* d; int base;
  if (bid < 4096)      { s = h;  d = hb;  base = bid; }
  else if (bid < 5120) { s = Wq; d = Wqb; base = bid - 4096; }
  else if (bid < 6144) { s = Wk; d = Wkb; base = bid - 5120; }
  else if (bid < 7168) { s = Wv; d = Wvb; base = bid - 6144; }
  else                 { s = Wo; d = Wob; base = bid - 7168; }
  const int i = (base * 256 + threadIdx.x) * 4;
  float4 f = *(const float4*)(s + i);
  union { unsigned short u[4]; uint2 v; } p;
  p.u[0] = bf16_bits(f.x); p.u[1] = bf16_bits(f.y);
  p.u[2] = bf16_bits(f.z); p.u[3] = bf16_bits(f.w);
  *(uint2*)(d + i) = p.v;
}

// QKV GEMM: C[M,N] = A[M,K] * B[N,K]^T ; bf16; fp32 accum; 16x16x32 MFMA.
// mat0 -> Qbuf row-major; mat1/mat2 -> Kt/Vt TRANSPOSED [bh][64][2048 m].
// XOR swizzle: LDS granule slot g of row r holds global granule g^(r&7).
// (256,3): grid 768 = 3 blocks/CU -> all co-resident, no half-empty tail round.
__global__ __launch_bounds__(256, 3)
void gemm_qkv(const bf16_t* __restrict__ A, int lda,
              const bf16_t* __restrict__ B0, const bf16_t* __restrict__ B1,
              const bf16_t* __restrict__ B2,
              bf16_t* __restrict__ Qbuf,
              bf16_t* __restrict__ Kt, bf16_t* __restrict__ Vt)
{
  __shared__ alignas(16) __bf16 As[BM * BK];
  __shared__ alignas(16) __bf16 Bs[BN * BK];

  const int t = threadIdx.x;
  const int lane = t & 63;
  const int wave = t >> 6;
  const int wm = wave >> 1;   // 0..1
  const int wn = wave & 1;    // 0..1

  const int m0 = blockIdx.x * BM;
  const int nblk = blockIdx.y * BN;
  const int mat = nblk >> 10;
  const bf16_t* __restrict__ B = (mat == 0) ? B0 : ((mat == 1) ? B1 : B2);
  const int n0 = nblk & 1023;

  floatx4 acc[4][4];
#pragma unroll
  for (int i = 0; i < 4; ++i)
#pragma unroll
    for (int j = 0; j < 4; ++j)
      acc[i][j] = (floatx4){0.f, 0.f, 0.f, 0.f};

  const int srow = t >> 3;   // staging row within 32-row chunk
  const int sgs = t & 7;     // LDS granule slot

  for (int k0 = 0; k0 < 1024; k0 += BK) {
#pragma unroll
    for (int r4 = 0; r4 < 4; ++r4) {
      const int row = r4 * 32 + srow;
      const int gsrc = sgs ^ (row & 7);
      async_load16(A + (size_t)(m0 + row) * lda + k0 + gsrc * 8,
                   &As[row * BK + sgs * 8]);
      async_load16(B + (size_t)(n0 + row) * 1024 + k0 + gsrc * 8,
                   &Bs[row * BK + sgs * 8]);
    }
    __syncthreads();
#pragma unroll
    for (int ks = 0; ks < 2; ++ks) {
      bf16x8 af[4], bfv[4];
#pragma unroll
      for (int i = 0; i < 4; ++i) {
        const int row = wm * 64 + i * 16 + (lane & 15);
        const int g = ks * 4 + (lane >> 4);
        af[i] = *(const bf16x8*)&As[row * BK + (g ^ (row & 7)) * 8];
      }
#pragma unroll
      for (int j = 0; j < 4; ++j) {
        const int row = wn * 64 + j * 16 + (lane & 15);
        const int g = ks * 4 + (lane >> 4);
        bfv[j] = *(const bf16x8*)&Bs[row * BK + (g ^ (row & 7)) * 8];
      }
#pragma unroll
      for (int i = 0; i < 4; ++i)
#pragma unroll
        for (int j = 0; j < 4; ++j)
          acc[i][j] = __builtin_amdgcn_mfma_f32_16x16x32_bf16(
              af[i], bfv[j], acc[i][j], 0, 0, 0);
    }
    __syncthreads();
  }

  const int ccol = lane & 15;
  const int crow = (lane >> 4) * 4;

  if (mat != 0) {
    bf16_t* __restrict__ T = (mat == 1) ? Kt : Vt;
#pragma unroll
    for (int i = 0; i < 4; ++i) {
#pragma unroll
      for (int j = 0; j < 4; ++j) {
        const int lc = n0 + wn * 64 + j * 16 + ccol;   // 0..1023
        const int hidx = lc >> 6, d = lc & 63;
        const int grow = m0 + wm * 64 + i * 16 + crow; // global row (incl b)
        const int bidx = grow >> 11, mloc = grow & 2047;
        union { unsigned short u[4]; uint2 v; } p;
#pragma unroll
        for (int r = 0; r < 4; ++r) p.u[r] = bf16_bits(acc[i][j][r]);
        *(uint2*)(T + (((size_t)bidx * 16 + hidx) * 64 + d) * 2048 + mloc) = p.v;
      }
    }
    return;
  }

#pragma unroll
  for (int i = 0; i < 4; ++i) {
#pragma unroll
    for (int j = 0; j < 4; ++j) {
      const int gcol = n0 + wn * 64 + j * 16 + ccol;
      const int growb = m0 + wm * 64 + i * 16 + crow;
#pragma unroll
      for (int r = 0; r < 4; ++r)
        Qbuf[(size_t)(growb + r) * 1024 + gcol] = __float2bfloat16(acc[i][j][r]);
    }
  }
}

// S[bh][d][e] += sum_m Kt[bh][d][m] * Vt[bh][e][m]  -- NT MFMA GEMM (16x16x32).
// grid (32 bh, 8 ksplit); fp32 atomic epilogue (tiny, L2-resident).
__global__ __launch_bounds__(256, 2)
void ktv_gemm(const bf16_t* __restrict__ Kt, const bf16_t* __restrict__ Vt,
              float* __restrict__ S)
{
  __shared__ alignas(16) __bf16 As[64 * 64];   // Kt tile (d rows)
  __shared__ alignas(16) __bf16 Bs[64 * 64];   // Vt tile (e rows)

  const int t = threadIdx.x;
  const int lane = t & 63;
  const int wave = t >> 6;            // d-strip = wave*16
  const int bh = blockIdx.x;
  const int kc = blockIdx.y;          // k-range kc*256 .. +256

  const bf16_t* A = Kt + (size_t)bh * 64 * 2048;
  const bf16_t* B = Vt + (size_t)bh * 64 * 2048;

  floatx4 acc[4];
#pragma unroll
  for (int j = 0; j < 4; ++j) acc[j] = (floatx4){0.f, 0.f, 0.f, 0.f};

  const int srow = t >> 3;   // 0..31
  const int sgs = t & 7;

  for (int k0 = kc * 256; k0 < kc * 256 + 256; k0 += 64) {
#pragma unroll
    for (int r2 = 0; r2 < 2; ++r2) {
      const int row = r2 * 32 + srow;
      const int gsrc = sgs ^ (row & 7);
      async_load16(A + (size_t)row * 2048 + k0 + gsrc * 8, &As[row * 64 + sgs * 8]);
      async_load16(B + (size_t)row * 2048 + k0 + gsrc * 8, &Bs[row * 64 + sgs * 8]);
    }
    __syncthreads();
#pragma unroll
    for (int ks = 0; ks < 2; ++ks) {
      bf16x8 af, bfv[4];
      {
        const int row = wave * 16 + (lane & 15);
        const int g = ks * 4 + (lane >> 4);
        af = *(const bf16x8*)&As[row * 64 + (g ^ (row & 7)) * 8];
      }
#pragma unroll
      for (int j = 0; j < 4; ++j) {
        const int row = j * 16 + (lane & 15);
        const int g = ks * 4 + (lane >> 4);
        bfv[j] = *(const bf16x8*)&Bs[row * 64 + (g ^ (row & 7)) * 8];
      }
#pragma unroll
      for (int j = 0; j < 4; ++j)
        acc[j] = __builtin_amdgcn_mfma_f32_16x16x32_bf16(af, bfv[j], acc[j], 0, 0, 0);
    }
    __syncthreads();
  }

  // C[d][e]: d = wave*16 + crow + r, e = j*16 + ccol
  const int ccol = lane & 15;
  const int crow = (lane >> 4) * 4;
  float* Sp = S + (size_t)bh * 4096;
#pragma unroll
  for (int j = 0; j < 4; ++j)
#pragma unroll
    for (int r = 0; r < 4; ++r)
      unsafeAtomicAdd(&Sp[(wave * 16 + crow + r) * 64 + j * 16 + ccol], acc[j][r]);
}

// W_effT[b][n][h*64+d] = sum_e Wo[n][h*64+e] * S[bh][d][e]   (16x16x32 MFMA)
__global__ __launch_bounds__(256, 2)
void weff_mfma(const bf16_t* __restrict__ Wob, const float* __restrict__ S,
               bf16_t* __restrict__ WeffT)
{
  __shared__ alignas(16) __bf16 Aw[128 * 64];
  __shared__ alignas(16) __bf16 Sb[64 * 64];

  const int t = threadIdx.x;
  const int lane = t & 63;
  const int wave = t >> 6;          // 0..3 -> 32-row n strip
  const int bh = blockIdx.x;
  const int b = bh >> 4, hh = bh & 15;
  const int nt = blockIdx.y;        // 0..7 -> 128 n rows

  const bf16_t* wbase = Wob + (size_t)(nt * 128) * 1024 + hh * 64;
  const int srow = t >> 3;          // 0..31
  const int sgs = t & 7;
#pragma unroll
  for (int r4 = 0; r4 < 4; ++r4) {
    const int row = r4 * 32 + srow;
    const int gsrc = sgs ^ (row & 7);
    async_load16(wbase + (size_t)row * 1024 + gsrc * 8, &Aw[row * 64 + sgs * 8]);
  }
  // stage S (fp32 -> bf16), XOR-swizzled; rows = d, cols = e
  {
    const int r = t >> 2;           // 0..63 (d row)
    const int g0 = (t & 3) * 2;
    const float* sp = S + (size_t)bh * 4096 + r * 64;
#pragma unroll
    for (int gg = 0; gg < 2; ++gg) {
      const int g = g0 + gg;
      const int gs = g ^ (r & 7);
      const float4 f0 = *(const float4*)(sp + gs * 8);
      const float4 f1 = *(const float4*)(sp + gs * 8 + 4);
      union { unsigned short u[8]; uint4 v; } pk;
      pk.u[0] = bf16_bits(f0.x); pk.u[1] = bf16_bits(f0.y);
      pk.u[2] = bf16_bits(f0.z); pk.u[3] = bf16_bits(f0.w);
      pk.u[4] = bf16_bits(f1.x); pk.u[5] = bf16_bits(f1.y);
      pk.u[6] = bf16_bits(f1.z); pk.u[7] = bf16_bits(f1.w);
      *(uint4*)&Sb[r * 64 + g * 8] = pk.v;
    }
  }
  __syncthreads();

  floatx4 acc[2][4];
#pragma unroll
  for (int i = 0; i < 2; ++i)
#pragma unroll
    for (int j = 0; j < 4; ++j)
      acc[i][j] = (floatx4){0.f, 0.f, 0.f, 0.f};

#pragma unroll
  for (int ks = 0; ks < 2; ++ks) {
    bf16x8 af[2], bfv[4];
#pragma unroll
    for (int i = 0; i < 2; ++i) {
      const int row = wave * 32 + i * 16 + (lane & 15);
      const int g = ks * 4 + (lane >> 4);
      af[i] = *(const bf16x8*)&Aw[row * 64 + (g ^ (row & 7)) * 8];
    }
#pragma unroll
    for (int j = 0; j < 4; ++j) {
      const int row = j * 16 + (lane & 15);       // d
      const int g = ks * 4 + (lane >> 4);
      bfv[j] = *(const bf16x8*)&Sb[row * 64 + (g ^ (row & 7)) * 8];
    }
#pragma unroll
    for (int i = 0; i < 2; ++i)
#pragma unroll
      for (int j = 0; j < 4; ++j)
        acc[i][j] = __builtin_amdgcn_mfma_f32_16x16x32_bf16(
            af[i], bfv[j], acc[i][j], 0, 0, 0);
  }

  const int ccol = lane & 15;
  const int crow = (lane >> 4) * 4;
  bf16_t* Wt = WeffT + (size_t)b * 1024 * 1024;
#pragma unroll
  for (int i = 0; i < 2; ++i) {
#pragma unroll
    for (int j = 0; j < 4; ++j) {
      const int hd = hh * 64 + j * 16 + ccol;
      const int n = nt * 128 + wave * 32 + i * 16 + crow;
#pragma unroll
      for (int r = 0; r < 4; ++r)
        Wt[(size_t)(n + r) * 1024 + hd] = __float2bfloat16(acc[i][j][r]);
    }
  }
}

// out[m][n] = sum_hd Q[m][hd] * WeffT[b][n][hd]. 16x16x32 MFMA, direct fp32 stores.
// BM=64 x BN=128 tiles -> grid (64,8) = 512 blocks = 2 blocks/CU.
__global__ __launch_bounds__(256, 2)
void gemm_final(const bf16_t* __restrict__ Q, const bf16_t* __restrict__ WeffT,
                float* __restrict__ C)
{
  __shared__ alignas(16) __bf16 As[64 * BK];    // Q tile
  __shared__ alignas(16) __bf16 Bs[128 * BK];   // WeffT tile

  const int t = threadIdx.x;
  const int lane = t & 63;
  const int wave = t >> 6;
  const int wm = wave >> 1;   // 0..1 (32-row strips)
  const int wn = wave & 1;    // 0..1 (64-col strips)

  const int m0 = blockIdx.x * 64;
  const int n0 = blockIdx.y * 128;
  const bf16_t* __restrict__ B = WeffT + (size_t)(m0 >> 11) * 1024 * 1024;

  floatx4 acc[2][4];
#pragma unroll
  for (int i = 0; i < 2; ++i)
#pragma unroll
    for (int j = 0; j < 4; ++j)
      acc[i][j] = (floatx4){0.f, 0.f, 0.f, 0.f};

  const int srow = t >> 3;
  const int sgs = t & 7;

  for (int k0 = 0; k0 < 1024; k0 += BK) {
#pragma unroll
    for (int r2 = 0; r2 < 2; ++r2) {
      const int row = r2 * 32 + srow;
      const int gsrc = sgs ^ (row & 7);
      async_load16(Q + (size_t)(m0 + row) * 1024 + k0 + gsrc * 8,
                   &As[row * BK + sgs * 8]);
    }
#pragma unroll
    for (int r4 = 0; r4 < 4; ++r4) {
      const int row = r4 * 32 + srow;
      const int gsrc = sgs ^ (row & 7);
      async_load16(B + (size_t)(n0 + row) * 1024 + k0 + gsrc * 8,
                   &Bs[row * BK + sgs * 8]);
    }
    __syncthreads();
#pragma unroll
    for (int ks = 0; ks < 2; ++ks) {
      bf16x8 af[2], bfv[4];
#pragma unroll
      for (int i = 0; i < 2; ++i) {
        const int row = wm * 32 + i * 16 + (lane & 15);
        const int g = ks * 4 + (lane >> 4);
        af[i] = *(const bf16x8*)&As[row * BK + (g ^ (row & 7)) * 8];
      }
#pragma unroll
      for (int j = 0; j < 4; ++j) {
        const int row = wn * 64 + j * 16 + (lane & 15);
        const int g = ks * 4 + (lane >> 4);
        bfv[j] = *(const bf16x8*)&Bs[row * BK + (g ^ (row & 7)) * 8];
      }
#pragma unroll
      for (int i = 0; i < 2; ++i)
#pragma unroll
        for (int j = 0; j < 4; ++j)
          acc[i][j] = __builtin_amdgcn_mfma_f32_16x16x32_bf16(
              af[i], bfv[j], acc[i][j], 0, 0, 0);
    }
    __syncthreads();
  }

  const int ccol = lane & 15;
  const int crow = (lane >> 4) * 4;
#pragma unroll
  for (int i = 0; i < 2; ++i) {
#pragma unroll
    for (int j = 0; j < 4; ++j) {
      const int gcol = n0 + wn * 64 + j * 16 + ccol;
      const int grow = m0 + wm * 32 + i * 16 + crow;
#pragma unroll
      for (int r = 0; r < 4; ++r)
        C[(size_t)(grow + r) * 1024 + gcol] = acc[i][j][r];
    }
  }
}

extern "C" void kernel_launch(void* const* d_in, const int* in_sizes, int n_in,
                              void* d_out, int out_size, void* d_ws, size_t ws_size,
                              hipStream_t stream)
{
  const float* h  = (const float*)d_in[0];
  const float* Wq = (const float*)d_in[1];
  const float* Wk = (const float*)d_in[2];
  const float* Wv = (const float*)d_in[3];
  // d_in[4] = Wspan: dead code in reference
  const float* Wo = (const float*)d_in[5];
  float* out = (float*)d_out;

  char* ws = (char*)d_ws;
  bf16_t* hb    = (bf16_t*)(ws);                 // [4096,1024] bf16, 8 MB (dead after QKV)
  bf16_t* WeffT = (bf16_t*)(ws);                 // [2][1024,1024] bf16, 4 MB (reuses hb)
  bf16_t* Wqb   = (bf16_t*)(ws + (8u << 20));    // 2 MB each
  bf16_t* Wkb   = (bf16_t*)(ws + (10u << 20));
  bf16_t* Wvb   = (bf16_t*)(ws + (12u << 20));
  bf16_t* Wob   = (bf16_t*)(ws + (14u << 20));
  bf16_t* Qbuf  = (bf16_t*)(ws + (16u << 20));   // [4096,1024] bf16, 8 MB
  bf16_t* Kt    = (bf16_t*)(ws + (24u << 20));   // [32][64][2048] bf16, 8 MB
  bf16_t* Vt    = (bf16_t*)(ws + (32u << 20));   // [32][64][2048] bf16, 8 MB
  float*  S     = (float*) (ws + (40u << 20));   // [32][64][64] fp32, d-major

  // conversions + S zero (one launch)
  cvt_all<<<dim3(8194), 256, 0, stream>>>(h, Wq, Wk, Wv, Wo, hb, Wqb, Wkb, Wvb, Wob, S);

  // Q -> Qbuf; K,V -> Kt,Vt (transposed, m-contiguous)
  gemm_qkv<<<dim3(32, 24), 256, 0, stream>>>(hb, 1024, Wqb, Wkb, Wvb, Qbuf, Kt, Vt);
  // S[bh][d][e] = sum_m K*V (MFMA NT, split-K=8, atomic fp32 on tiny S)
  ktv_gemm<<<dim3(32, 8), 256, 0, stream>>>(Kt, Vt, S);
  // W_effT[b][n][hd] = sum_e Wo[n][he] * S[bh][d][e]  (overwrites dead hb)
  weff_mfma<<<dim3(32, 8), 256, 0, stream>>>(Wob, S, WeffT);
  // out = Q @ W_effT^T, direct fp32 stores, 2 blocks/CU
  gemm_final<<<dim3(64, 8), 256, 0, stream>>>(Qbuf, WeffT, out);
}

// Round 11
// 141.914 us; speedup vs baseline: 1.0403x; 1.0081x over previous
//
#include <hip/hip_runtime.h>
#include <hip/hip_bf16.h>
#include <stdint.h>

typedef __hip_bfloat16 bf16_t;
typedef __attribute__((ext_vector_type(8))) __bf16 bf16x8;
typedef __attribute__((ext_vector_type(4))) float floatx4;

#define BM 128
#define BN 128
#define BK 64

// async 16B global->LDS (wave-uniform LDS base + lane*16; our layouts satisfy this)
__device__ inline void async_load16(const void* g, void* l) {
  __builtin_amdgcn_global_load_lds(
      (const __attribute__((address_space(1))) unsigned int*)g,
      (__attribute__((address_space(3))) unsigned int*)l,
      16, 0, 0);
}

__device__ inline unsigned short bf16_bits(float f) {
  bf16_t b = __float2bfloat16(f);
  return *(const unsigned short*)&b;
}

// fp32 -> bf16 for all 5 tensors + S zero-init, one launch.
__global__ void cvt_all(const float* __restrict__ h, const float* __restrict__ Wq,
                        const float* __restrict__ Wk, const float* __restrict__ Wv,
                        const float* __restrict__ Wo,
                        bf16_t* __restrict__ hb, bf16_t* __restrict__ Wqb,
                        bf16_t* __restrict__ Wkb, bf16_t* __restrict__ Wvb,
                        bf16_t* __restrict__ Wob, float* __restrict__ S)
{
  const int bid = blockIdx.x;
  if (bid >= 8192) {
    float4* s4 = (float4*)S;      // 131072 floats = 32768 float4
    const int base = (bid - 8192) * 256 + threadIdx.x;   // 0..511
#pragma unroll
    for (int i = 0; i < 64; ++i)
      s4[base + i * 512] = (float4){0.f, 0.f, 0.f, 0.f};
    return;
  }
  const float* s; bf16_t* d; int base;
  if (bid < 4096)      { s = h;  d = hb;  base = bid; }
  else if (bid < 5120) { s = Wq; d = Wqb; base = bid - 4096; }
  else if (bid < 6144) { s = Wk; d = Wkb; base = bid - 5120; }
  else if (bid < 7168) { s = Wv; d = Wvb; base = bid - 6144; }
  else                 { s = Wo; d = Wob; base = bid - 7168; }
  const int i = (base * 256 + threadIdx.x) * 4;
  float4 f = *(const float4*)(s + i);
  union { unsigned short u[4]; uint2 v; } p;
  p.u[0] = bf16_bits(f.x); p.u[1] = bf16_bits(f.y);
  p.u[2] = bf16_bits(f.z); p.u[3] = bf16_bits(f.w);
  *(uint2*)(d + i) = p.v;
}

// QKV GEMM: C[M,N] = A[M,K] * B[N,K]^T ; bf16; fp32 accum; 16x16x32 MFMA.
// mat0 -> Qbuf row-major; mat1/mat2 -> Kt/Vt TRANSPOSED [bh][64][2048 m].
// XOR swizzle: LDS granule slot g of row r holds global granule g^(r&7).
// (256,2): R8-proven best config — (256,3) measured neutral (R10).
__global__ __launch_bounds__(256, 2)
void gemm_qkv(const bf16_t* __restrict__ A, int lda,
              const bf16_t* __restrict__ B0, const bf16_t* __restrict__ B1,
              const bf16_t* __restrict__ B2,
              bf16_t* __restrict__ Qbuf,
              bf16_t* __restrict__ Kt, bf16_t* __restrict__ Vt)
{
  __shared__ alignas(16) __bf16 As[BM * BK];
  __shared__ alignas(16) __bf16 Bs[BN * BK];

  const int t = threadIdx.x;
  const int lane = t & 63;
  const int wave = t >> 6;
  const int wm = wave >> 1;   // 0..1
  const int wn = wave & 1;    // 0..1

  const int m0 = blockIdx.x * BM;
  const int nblk = blockIdx.y * BN;
  const int mat = nblk >> 10;
  const bf16_t* __restrict__ B = (mat == 0) ? B0 : ((mat == 1) ? B1 : B2);
  const int n0 = nblk & 1023;

  floatx4 acc[4][4];
#pragma unroll
  for (int i = 0; i < 4; ++i)
#pragma unroll
    for (int j = 0; j < 4; ++j)
      acc[i][j] = (floatx4){0.f, 0.f, 0.f, 0.f};

  const int srow = t >> 3;   // staging row within 32-row chunk
  const int sgs = t & 7;     // LDS granule slot

  for (int k0 = 0; k0 < 1024; k0 += BK) {
#pragma unroll
    for (int r4 = 0; r4 < 4; ++r4) {
      const int row = r4 * 32 + srow;
      const int gsrc = sgs ^ (row & 7);
      async_load16(A + (size_t)(m0 + row) * lda + k0 + gsrc * 8,
                   &As[row * BK + sgs * 8]);
      async_load16(B + (size_t)(n0 + row) * 1024 + k0 + gsrc * 8,
                   &Bs[row * BK + sgs * 8]);
    }
    __syncthreads();
#pragma unroll
    for (int ks = 0; ks < 2; ++ks) {
      bf16x8 af[4], bfv[4];
#pragma unroll
      for (int i = 0; i < 4; ++i) {
        const int row = wm * 64 + i * 16 + (lane & 15);
        const int g = ks * 4 + (lane >> 4);
        af[i] = *(const bf16x8*)&As[row * BK + (g ^ (row & 7)) * 8];
      }
#pragma unroll
      for (int j = 0; j < 4; ++j) {
        const int row = wn * 64 + j * 16 + (lane & 15);
        const int g = ks * 4 + (lane >> 4);
        bfv[j] = *(const bf16x8*)&Bs[row * BK + (g ^ (row & 7)) * 8];
      }
#pragma unroll
      for (int i = 0; i < 4; ++i)
#pragma unroll
        for (int j = 0; j < 4; ++j)
          acc[i][j] = __builtin_amdgcn_mfma_f32_16x16x32_bf16(
              af[i], bfv[j], acc[i][j], 0, 0, 0);
    }
    __syncthreads();
  }

  const int ccol = lane & 15;
  const int crow = (lane >> 4) * 4;

  if (mat != 0) {
    bf16_t* __restrict__ T = (mat == 1) ? Kt : Vt;
#pragma unroll
    for (int i = 0; i < 4; ++i) {
#pragma unroll
      for (int j = 0; j < 4; ++j) {
        const int lc = n0 + wn * 64 + j * 16 + ccol;   // 0..1023
        const int hidx = lc >> 6, d = lc & 63;
        const int grow = m0 + wm * 64 + i * 16 + crow; // global row (incl b)
        const int bidx = grow >> 11, mloc = grow & 2047;
        union { unsigned short u[4]; uint2 v; } p;
#pragma unroll
        for (int r = 0; r < 4; ++r) p.u[r] = bf16_bits(acc[i][j][r]);
        *(uint2*)(T + (((size_t)bidx * 16 + hidx) * 64 + d) * 2048 + mloc) = p.v;
      }
    }
    return;
  }

#pragma unroll
  for (int i = 0; i < 4; ++i) {
#pragma unroll
    for (int j = 0; j < 4; ++j) {
      const int gcol = n0 + wn * 64 + j * 16 + ccol;
      const int growb = m0 + wm * 64 + i * 16 + crow;
#pragma unroll
      for (int r = 0; r < 4; ++r)
        Qbuf[(size_t)(growb + r) * 1024 + gcol] = __float2bfloat16(acc[i][j][r]);
    }
  }
}

// S[bh][d][e] += sum_m Kt[bh][d][m] * Vt[bh][e][m]  -- NT MFMA GEMM (16x16x32).
// grid (32 bh, 8 ksplit); fp32 atomic epilogue (tiny, L2-resident).
__global__ __launch_bounds__(256, 2)
void ktv_gemm(const bf16_t* __restrict__ Kt, const bf16_t* __restrict__ Vt,
              float* __restrict__ S)
{
  __shared__ alignas(16) __bf16 As[64 * 64];   // Kt tile (d rows)
  __shared__ alignas(16) __bf16 Bs[64 * 64];   // Vt tile (e rows)

  const int t = threadIdx.x;
  const int lane = t & 63;
  const int wave = t >> 6;            // d-strip = wave*16
  const int bh = blockIdx.x;
  const int kc = blockIdx.y;          // k-range kc*256 .. +256

  const bf16_t* A = Kt + (size_t)bh * 64 * 2048;
  const bf16_t* B = Vt + (size_t)bh * 64 * 2048;

  floatx4 acc[4];
#pragma unroll
  for (int j = 0; j < 4; ++j) acc[j] = (floatx4){0.f, 0.f, 0.f, 0.f};

  const int srow = t >> 3;   // 0..31
  const int sgs = t & 7;

  for (int k0 = kc * 256; k0 < kc * 256 + 256; k0 += 64) {
#pragma unroll
    for (int r2 = 0; r2 < 2; ++r2) {
      const int row = r2 * 32 + srow;
      const int gsrc = sgs ^ (row & 7);
      async_load16(A + (size_t)row * 2048 + k0 + gsrc * 8, &As[row * 64 + sgs * 8]);
      async_load16(B + (size_t)row * 2048 + k0 + gsrc * 8, &Bs[row * 64 + sgs * 8]);
    }
    __syncthreads();
#pragma unroll
    for (int ks = 0; ks < 2; ++ks) {
      bf16x8 af, bfv[4];
      {
        const int row = wave * 16 + (lane & 15);
        const int g = ks * 4 + (lane >> 4);
        af = *(const bf16x8*)&As[row * 64 + (g ^ (row & 7)) * 8];
      }
#pragma unroll
      for (int j = 0; j < 4; ++j) {
        const int row = j * 16 + (lane & 15);
        const int g = ks * 4 + (lane >> 4);
        bfv[j] = *(const bf16x8*)&Bs[row * 64 + (g ^ (row & 7)) * 8];
      }
#pragma unroll
      for (int j = 0; j < 4; ++j)
        acc[j] = __builtin_amdgcn_mfma_f32_16x16x32_bf16(af, bfv[j], acc[j], 0, 0, 0);
    }
    __syncthreads();
  }

  // C[d][e]: d = wave*16 + crow + r, e = j*16 + ccol
  const int ccol = lane & 15;
  const int crow = (lane >> 4) * 4;
  float* Sp = S + (size_t)bh * 4096;
#pragma unroll
  for (int j = 0; j < 4; ++j)
#pragma unroll
    for (int r = 0; r < 4; ++r)
      unsafeAtomicAdd(&Sp[(wave * 16 + crow + r) * 64 + j * 16 + ccol], acc[j][r]);
}

// W_effT[b][n][h*64+d] = sum_e Wo[n][h*64+e] * S[bh][d][e]   (16x16x32 MFMA)
__global__ __launch_bounds__(256, 2)
void weff_mfma(const bf16_t* __restrict__ Wob, const float* __restrict__ S,
               bf16_t* __restrict__ WeffT)
{
  __shared__ alignas(16) __bf16 Aw[128 * 64];
  __shared__ alignas(16) __bf16 Sb[64 * 64];

  const int t = threadIdx.x;
  const int lane = t & 63;
  const int wave = t >> 6;          // 0..3 -> 32-row n strip
  const int bh = blockIdx.x;
  const int b = bh >> 4, hh = bh & 15;
  const int nt = blockIdx.y;        // 0..7 -> 128 n rows

  const bf16_t* wbase = Wob + (size_t)(nt * 128) * 1024 + hh * 64;
  const int srow = t >> 3;          // 0..31
  const int sgs = t & 7;
#pragma unroll
  for (int r4 = 0; r4 < 4; ++r4) {
    const int row = r4 * 32 + srow;
    const int gsrc = sgs ^ (row & 7);
    async_load16(wbase + (size_t)row * 1024 + gsrc * 8, &Aw[row * 64 + sgs * 8]);
  }
  // stage S (fp32 -> bf16), XOR-swizzled; rows = d, cols = e
  {
    const int r = t >> 2;           // 0..63 (d row)
    const int g0 = (t & 3) * 2;
    const float* sp = S + (size_t)bh * 4096 + r * 64;
#pragma unroll
    for (int gg = 0; gg < 2; ++gg) {
      const int g = g0 + gg;
      const int gs = g ^ (r & 7);
      const float4 f0 = *(const float4*)(sp + gs * 8);
      const float4 f1 = *(const float4*)(sp + gs * 8 + 4);
      union { unsigned short u[8]; uint4 v; } pk;
      pk.u[0] = bf16_bits(f0.x); pk.u[1] = bf16_bits(f0.y);
      pk.u[2] = bf16_bits(f0.z); pk.u[3] = bf16_bits(f0.w);
      pk.u[4] = bf16_bits(f1.x); pk.u[5] = bf16_bits(f1.y);
      pk.u[6] = bf16_bits(f1.z); pk.u[7] = bf16_bits(f1.w);
      *(uint4*)&Sb[r * 64 + g * 8] = pk.v;
    }
  }
  __syncthreads();

  floatx4 acc[2][4];
#pragma unroll
  for (int i = 0; i < 2; ++i)
#pragma unroll
    for (int j = 0; j < 4; ++j)
      acc[i][j] = (floatx4){0.f, 0.f, 0.f, 0.f};

#pragma unroll
  for (int ks = 0; ks < 2; ++ks) {
    bf16x8 af[2], bfv[4];
#pragma unroll
    for (int i = 0; i < 2; ++i) {
      const int row = wave * 32 + i * 16 + (lane & 15);
      const int g = ks * 4 + (lane >> 4);
      af[i] = *(const bf16x8*)&Aw[row * 64 + (g ^ (row & 7)) * 8];
    }
#pragma unroll
    for (int j = 0; j < 4; ++j) {
      const int row = j * 16 + (lane & 15);       // d
      const int g = ks * 4 + (lane >> 4);
      bfv[j] = *(const bf16x8*)&Sb[row * 64 + (g ^ (row & 7)) * 8];
    }
#pragma unroll
    for (int i = 0; i < 2; ++i)
#pragma unroll
      for (int j = 0; j < 4; ++j)
        acc[i][j] = __builtin_amdgcn_mfma_f32_16x16x32_bf16(
            af[i], bfv[j], acc[i][j], 0, 0, 0);
  }

  const int ccol = lane & 15;
  const int crow = (lane >> 4) * 4;
  bf16_t* Wt = WeffT + (size_t)b * 1024 * 1024;
#pragma unroll
  for (int i = 0; i < 2; ++i) {
#pragma unroll
    for (int j = 0; j < 4; ++j) {
      const int hd = hh * 64 + j * 16 + ccol;
      const int n = nt * 128 + wave * 32 + i * 16 + crow;
#pragma unroll
      for (int r = 0; r < 4; ++r)
        Wt[(size_t)(n + r) * 1024 + hd] = __float2bfloat16(acc[i][j][r]);
    }
  }
}

// out[m][n] = sum_hd Q[m][hd] * WeffT[b][n][hd]. 16x16x32 MFMA, direct fp32 stores.
// BM=64 x BN=128 tiles -> grid (64,8) = 512 blocks = 2 blocks/CU.
__global__ __launch_bounds__(256, 2)
void gemm_final(const bf16_t* __restrict__ Q, const bf16_t* __restrict__ WeffT,
                float* __restrict__ C)
{
  __shared__ alignas(16) __bf16 As[64 * BK];    // Q tile
  __shared__ alignas(16) __bf16 Bs[128 * BK];   // WeffT tile

  const int t = threadIdx.x;
  const int lane = t & 63;
  const int wave = t >> 6;
  const int wm = wave >> 1;   // 0..1 (32-row strips)
  const int wn = wave & 1;    // 0..1 (64-col strips)

  const int m0 = blockIdx.x * 64;
  const int n0 = blockIdx.y * 128;
  const bf16_t* __restrict__ B = WeffT + (size_t)(m0 >> 11) * 1024 * 1024;

  floatx4 acc[2][4];
#pragma unroll
  for (int i = 0; i < 2; ++i)
#pragma unroll
    for (int j = 0; j < 4; ++j)
      acc[i][j] = (floatx4){0.f, 0.f, 0.f, 0.f};

  const int srow = t >> 3;
  const int sgs = t & 7;

  for (int k0 = 0; k0 < 1024; k0 += BK) {
#pragma unroll
    for (int r2 = 0; r2 < 2; ++r2) {
      const int row = r2 * 32 + srow;
      const int gsrc = sgs ^ (row & 7);
      async_load16(Q + (size_t)(m0 + row) * 1024 + k0 + gsrc * 8,
                   &As[row * BK + sgs * 8]);
    }
#pragma unroll
    for (int r4 = 0; r4 < 4; ++r4) {
      const int row = r4 * 32 + srow;
      const int gsrc = sgs ^ (row & 7);
      async_load16(B + (size_t)(n0 + row) * 1024 + k0 + gsrc * 8,
                   &Bs[row * BK + sgs * 8]);
    }
    __syncthreads();
#pragma unroll
    for (int ks = 0; ks < 2; ++ks) {
      bf16x8 af[2], bfv[4];
#pragma unroll
      for (int i = 0; i < 2; ++i) {
        const int row = wm * 32 + i * 16 + (lane & 15);
        const int g = ks * 4 + (lane >> 4);
        af[i] = *(const bf16x8*)&As[row * BK + (g ^ (row & 7)) * 8];
      }
#pragma unroll
      for (int j = 0; j < 4; ++j) {
        const int row = wn * 64 + j * 16 + (lane & 15);
        const int g = ks * 4 + (lane >> 4);
        bfv[j] = *(const bf16x8*)&Bs[row * BK + (g ^ (row & 7)) * 8];
      }
#pragma unroll
      for (int i = 0; i < 2; ++i)
#pragma unroll
        for (int j = 0; j < 4; ++j)
          acc[i][j] = __builtin_amdgcn_mfma_f32_16x16x32_bf16(
              af[i], bfv[j], acc[i][j], 0, 0, 0);
    }
    __syncthreads();
  }

  const int ccol = lane & 15;
  const int crow = (lane >> 4) * 4;
#pragma unroll
  for (int i = 0; i < 2; ++i) {
#pragma unroll
    for (int j = 0; j < 4; ++j) {
      const int gcol = n0 + wn * 64 + j * 16 + ccol;
      const int grow = m0 + wm * 32 + i * 16 + crow;
#pragma unroll
      for (int r = 0; r < 4; ++r)
        C[(size_t)(grow + r) * 1024 + gcol] = acc[i][j][r];
    }
  }
}

extern "C" void kernel_launch(void* const* d_in, const int* in_sizes, int n_in,
                              void* d_out, int out_size, void* d_ws, size_t ws_size,
                              hipStream_t stream)
{
  const float* h  = (const float*)d_in[0];
  const float* Wq = (const float*)d_in[1];
  const float* Wk = (const float*)d_in[2];
  const float* Wv = (const float*)d_in[3];
  // d_in[4] = Wspan: dead code in reference
  const float* Wo = (const float*)d_in[5];
  float* out = (float*)d_out;

  char* ws = (char*)d_ws;
  bf16_t* hb    = (bf16_t*)(ws);                 // [4096,1024] bf16, 8 MB (dead after QKV)
  bf16_t* WeffT = (bf16_t*)(ws);                 // [2][1024,1024] bf16, 4 MB (reuses hb)
  bf16_t* Wqb   = (bf16_t*)(ws + (8u << 20));    // 2 MB each
  bf16_t* Wkb   = (bf16_t*)(ws + (10u << 20));
  bf16_t* Wvb   = (bf16_t*)(ws + (12u << 20));
  bf16_t* Wob   = (bf16_t*)(ws + (14u << 20));
  bf16_t* Qbuf  = (bf16_t*)(ws + (16u << 20));   // [4096,1024] bf16, 8 MB
  bf16_t* Kt    = (bf16_t*)(ws + (24u << 20));   // [32][64][2048] bf16, 8 MB
  bf16_t* Vt    = (bf16_t*)(ws + (32u << 20));   // [32][64][2048] bf16, 8 MB
  float*  S     = (float*) (ws + (40u << 20));   // [32][64][64] fp32, d-major

  // conversions + S zero (one launch)
  cvt_all<<<dim3(8194), 256, 0, stream>>>(h, Wq, Wk, Wv, Wo, hb, Wqb, Wkb, Wvb, Wob, S);

  // Q -> Qbuf; K,V -> Kt,Vt (transposed, m-contiguous)
  gemm_qkv<<<dim3(32, 24), 256, 0, stream>>>(hb, 1024, Wqb, Wkb, Wvb, Qbuf, Kt, Vt);
  // S[bh][d][e] = sum_m K*V (MFMA NT, split-K=8, atomic fp32 on tiny S)
  ktv_gemm<<<dim3(32, 8), 256, 0, stream>>>(Kt, Vt, S);
  // W_effT[b][n][hd] = sum_e Wo[n][he] * S[bh][d][e]  (overwrites dead hb)
  weff_mfma<<<dim3(32, 8), 256, 0, stream>>>(Wob, S, WeffT);
  // out = Q @ W_effT^T, direct fp32 stores, 2 blocks/CU
  gemm_final<<<dim3(64, 8), 256, 0, stream>>>(Qbuf, WeffT, out);
}